// Round 12
// baseline (312.723 us; speedup 1.0000x reference)
//
#include <hip/hip_runtime.h>
#include <hip/hip_bf16.h>
#include <math.h>

#define DIM 256
#define HDIM 32
#define NN 4096
#define NM (NN * DIM)
// (1/sqrt(256)) * log2(e) -- folded into WQ so scores are in exp2 domain
#define PREF 0.09016844005555896f
#define LEAKY 0.2f
#define BCAP 128   // edge-bucket capacity per dst (Poisson(32): P(deg>128) ~ 0)

typedef __attribute__((ext_vector_type(8))) short short8;
typedef __attribute__((ext_vector_type(16))) float f32x16;

#if __has_builtin(__builtin_amdgcn_exp2f)
#define EXP2(x) __builtin_amdgcn_exp2f(x)   // raw v_exp_f32: scores bounded, no fixups needed
#else
#define EXP2(x) exp2f(x)
#endif

static __device__ __forceinline__ unsigned bfbits(float x) {
  unsigned u = __float_as_uint(x);
  return (u + 0x7fffu + ((u >> 16) & 1u)) >> 16;   // RNE f32->bf16 bits
}
static __device__ __forceinline__ float bf2f(unsigned short b) {
  return __uint_as_float(((unsigned)b) << 16);
}
static __device__ __forceinline__ unsigned pk_bf16(float lo, float hi) {
  __hip_bfloat162 t = __float22bfloat162_rn(make_float2(lo, hi));  // v_cvt_pk_bf16_f32
  return *(unsigned*)&t;
}

// ---- convert: Wtb[w][n][k] = bf16(W_w[k][n]*scale); grid (16,4); y==0 blocks zero cnt
__global__ __launch_bounds__(256) void convert_w(
    const float* __restrict__ W0, const float* __restrict__ W1,
    const float* __restrict__ W2, const float* __restrict__ W3,
    unsigned short* __restrict__ Wtb, int* __restrict__ cnt) {
  const int tid = threadIdx.x;
  if (blockIdx.y == 0) cnt[blockIdx.x * 256 + tid] = 0;   // 16x256 = 4096 ints
  __shared__ float tile[64][68];
  const int wsel = blockIdx.y;
  const float* W = wsel == 0 ? W0 : (wsel == 1 ? W1 : (wsel == 2 ? W2 : W3));
  const float scale = wsel == 0 ? PREF : 1.f;
  const int kb = (blockIdx.x & 3) * 64, nb = (blockIdx.x >> 2) * 64;
#pragma unroll
  for (int i = 0; i < 4; ++i) {
    int idx = i * 256 + tid;
    int kr = idx >> 4, ns = idx & 15;
    float4 v = *(const float4*)&W[(kb + kr) * DIM + nb + ns * 4];
    tile[kr][ns * 4 + 0] = v.x; tile[kr][ns * 4 + 1] = v.y;
    tile[kr][ns * 4 + 2] = v.z; tile[kr][ns * 4 + 3] = v.w;
  }
  __syncthreads();
  unsigned short* o = Wtb + wsel * 65536;
#pragma unroll
  for (int i = 0; i < 2; ++i) {
    int idx = i * 256 + tid;
    int nr = idx >> 3, kslot = idx & 7;
    short8 v;
#pragma unroll
    for (int j = 0; j < 8; ++j)
      ((unsigned short*)&v)[j] = (unsigned short)bfbits(tile[kslot * 8 + j][nr] * scale);
    *(short8*)&o[(nb + nr) * DIM + kb + kslot * 8] = v;
  }
}

// ---------------- fused: QKV GEMM (blocks 0..255) + edge-bucket fill (blocks 256+) ----
__global__ __launch_bounds__(256) void gemm_fill(
    const float* __restrict__ inp, const unsigned short* __restrict__ Wtb,
    const int* __restrict__ src, const int* __restrict__ dst, int E,
    int* __restrict__ cnt, int* __restrict__ esrc,
    unsigned short* __restrict__ Qb, unsigned short* __restrict__ Kb,
    unsigned short* __restrict__ Vtb) {
  __shared__ __align__(16) short sA[64 * 256];   // 32 KB
  __shared__ __align__(16) short sB[64 * 256];   // 32 KB
  const int tid = threadIdx.x;
  const int b = blockIdx.x;
  if (b >= 256) {                  // fill: slot = atomicAdd(cnt[d]); esrc[d*BCAP+slot]=src
    int e = (b - 256) * 256 + tid;
    if (e < E) {
      int d = dst[e];
      int p = atomicAdd(&cnt[d], 1);
      if (p < BCAP) esrc[d * BCAP + p] = src[e];
    }
    return;
  }
  const int m0 = (b & 63) * 64;
  const int n0 = (b >> 6) * 64;
  // stage A once: f32 -> bf16 during copy (64 rows x 64 slots x 4 f32)
#pragma unroll
  for (int i = 0; i < 16; ++i) {
    int idx = i * 256 + tid;
    int row = idx >> 6, slot = idx & 63;
    float4 v = *(const float4*)&inp[(m0 + row) * DIM + slot * 4];
    uint2 pk = make_uint2(pk_bf16(v.x, v.y), pk_bf16(v.z, v.w));
    int byte = (slot * 8) ^ ((row & 15) << 4);
    *(uint2*)((char*)sA + row * 512 + byte) = pk;
  }
  const int kl = tid & 31, hi = (tid & 63) >> 5, w = tid >> 6;
  const int rw = (w >> 1) * 32, cw = (w & 1) * 32;
  const int arow = rw + kl, brow = cw + kl;
  const int axor = (arow & 15) << 4, bxor = (brow & 15) << 4;
  const char* apA = (const char*)sA + arow * 512;
  const char* apB = (const char*)sB + brow * 512;

#pragma unroll 1
  for (int wsel = 0; wsel < 3; ++wsel) {
    const unsigned short* Wt = Wtb + wsel * 65536;
    __syncthreads();               // prev compute done reading sB (wsel0: none)
#pragma unroll
    for (int i = 0; i < 8; ++i) {
      int idx = i * 256 + tid;
      int row = idx >> 5, slot = idx & 31;
      short8 v = *(const short8*)&Wt[(n0 + row) * DIM + slot * 8];
      int byte = (slot * 16) ^ ((row & 15) << 4);
      *(short8*)((char*)sB + row * 512 + byte) = v;
    }
    __syncthreads();               // sB (and sA on first iter) visible
    f32x16 acc;
#pragma unroll
    for (int r = 0; r < 16; ++r) acc[r] = 0.f;
#pragma unroll
    for (int ks = 0; ks < 16; ++ks) {
      int cb = ks * 32 + hi * 16;
      short8 a = *(const short8*)(apA + (cb ^ axor));
      short8 bfr = *(const short8*)(apB + (cb ^ bxor));
      acc = __builtin_amdgcn_mfma_f32_32x32x16_bf16(a, bfr, acc, 0, 0, 0);
    }
    if (wsel < 2) {
      unsigned short* C = wsel == 0 ? Qb : Kb;
#pragma unroll
      for (int r = 0; r < 16; ++r) {
        int mrow = (r & 3) + 8 * (r >> 2) + 4 * hi;
        C[(m0 + rw + mrow) * DIM + n0 + cw + kl] = (unsigned short)bfbits(acc[r]);
      }
    } else {
      // V: transpose via LDS (sB reused as [64 m][72] ushort tile) -> Vtb[dim][node]
      __syncthreads();             // all waves done reading sB
      unsigned short* tile = (unsigned short*)sB;
#pragma unroll
      for (int r = 0; r < 16; ++r) {
        int mrow = (r & 3) + 8 * (r >> 2) + 4 * hi;
        tile[(rw + mrow) * 72 + cw + kl] = (unsigned short)bfbits(acc[r]);
      }
      __syncthreads();
#pragma unroll
      for (int i = 0; i < 2; ++i) {
        int idx = i * 256 + tid;
        int drow = idx >> 3, nslot = idx & 7;
        short8 v;
#pragma unroll
        for (int j = 0; j < 8; ++j)
          ((unsigned short*)&v)[j] = tile[(nslot * 8 + j) * 72 + drow];
        *(short8*)&Vtb[(n0 + drow) * NN + m0 + nslot * 8] = v;
      }
    }
  }
}

// ---------------- K2 gather from buckets: wave per dst node, ILP-4 ----------------
__global__ __launch_bounds__(256) void gather_k2(
    const unsigned short* __restrict__ Kb, const int* __restrict__ cnt,
    const int* __restrict__ esrc, unsigned short* __restrict__ K2b) {
  int w = threadIdx.x >> 6, lane = threadIdx.x & 63;
  int d = blockIdx.x * 4 + w;
  int n = cnt[d]; n = n > BCAP ? BCAP : n;
  const int* eb = esrc + d * BCAP;
  float a0 = 0, a1 = 0, a2 = 0, a3 = 0;
  int j = 0;
  for (; j + 4 <= n; j += 4) {     // 4 independent load chains in flight
    int s0 = eb[j], s1 = eb[j + 1], s2 = eb[j + 2], s3 = eb[j + 3];
    ushort4 k0 = *(const ushort4*)&Kb[s0 * DIM + lane * 4];
    ushort4 k1 = *(const ushort4*)&Kb[s1 * DIM + lane * 4];
    ushort4 k2 = *(const ushort4*)&Kb[s2 * DIM + lane * 4];
    ushort4 k3 = *(const ushort4*)&Kb[s3 * DIM + lane * 4];
    a0 += bf2f(k0.x) + bf2f(k1.x) + bf2f(k2.x) + bf2f(k3.x);
    a1 += bf2f(k0.y) + bf2f(k1.y) + bf2f(k2.y) + bf2f(k3.y);
    a2 += bf2f(k0.z) + bf2f(k1.z) + bf2f(k2.z) + bf2f(k3.z);
    a3 += bf2f(k0.w) + bf2f(k1.w) + bf2f(k2.w) + bf2f(k3.w);
  }
  for (; j < n; ++j) {
    int s = eb[j];
    ushort4 kv = *(const ushort4*)&Kb[s * DIM + lane * 4];
    a0 += bf2f(kv.x); a1 += bf2f(kv.y); a2 += bf2f(kv.z); a3 += bf2f(kv.w);
  }
  ushort4 o;
  o.x = bfbits(a0); o.y = bfbits(a1); o.z = bfbits(a2); o.w = bfbits(a3);
  *(ushort4*)&K2b[d * DIM + lane * 4] = o;
}

// ---- per-tile compute (64-key tile, 2 subs): QK^T -> exp2 -> pack/permlane -> PV ----
static __device__ __forceinline__ void compute_tile64(
    const short* __restrict__ lk, const short* __restrict__ lv, int kl, int hi,
    short8 qf0, short8 qf1, const f32x16& zc, f32x16& o, float& lsum) {
#pragma unroll
  for (int sub = 0; sub < 2; ++sub) {
    const int base = sub * 32;
    short8 a0 = *(const short8*)&lk[(base + kl) * 40 + hi * 8];
    short8 a1 = *(const short8*)&lk[(base + kl) * 40 + 16 + hi * 8];
    __builtin_amdgcn_s_setprio(1);
    f32x16 c = __builtin_amdgcn_mfma_f32_32x32x16_bf16(a0, qf0, zc, 0, 0, 0);
    c = __builtin_amdgcn_mfma_f32_32x32x16_bf16(a1, qf1, c, 0, 0, 0);
    __builtin_amdgcn_s_setprio(0);
    float p[16];
#pragma unroll
    for (int r = 0; r < 16; ++r) p[r] = EXP2(c[r]);
    {  // scalar tree-sum
      float t0 = (p[0] + p[1]) + (p[2] + p[3]);
      float t1 = (p[4] + p[5]) + (p[6] + p[7]);
      float t2 = (p[8] + p[9]) + (p[10] + p[11]);
      float t3 = (p[12] + p[13]) + (p[14] + p[15]);
      lsum += (t0 + t1) + (t2 + t3);
    }
    unsigned X0 = pk_bf16(p[0], p[1]);
    unsigned Y0 = pk_bf16(p[2], p[3]);
    unsigned Z0 = pk_bf16(p[4], p[5]);
    unsigned W0 = pk_bf16(p[6], p[7]);
    asm volatile("v_permlane32_swap_b32 %0, %1" : "+v"(X0), "+v"(Z0));
    asm volatile("v_permlane32_swap_b32 %0, %1" : "+v"(Y0), "+v"(W0));
    unsigned X1 = pk_bf16(p[8], p[9]);
    unsigned Y1 = pk_bf16(p[10], p[11]);
    unsigned Z1 = pk_bf16(p[12], p[13]);
    unsigned W1 = pk_bf16(p[14], p[15]);
    asm volatile("v_permlane32_swap_b32 %0, %1" : "+v"(X1), "+v"(Z1));
    asm volatile("v_permlane32_swap_b32 %0, %1" : "+v"(Y1), "+v"(W1));
    short8 pb0, pb1;
    ((unsigned*)&pb0)[0] = X0; ((unsigned*)&pb0)[1] = Y0;
    ((unsigned*)&pb0)[2] = Z0; ((unsigned*)&pb0)[3] = W0;
    ((unsigned*)&pb1)[0] = X1; ((unsigned*)&pb1)[1] = Y1;
    ((unsigned*)&pb1)[2] = Z1; ((unsigned*)&pb1)[3] = W1;
    short8 va0 = *(const short8*)&lv[kl * 72 + base + hi * 8];
    short8 va1 = *(const short8*)&lv[kl * 72 + base + 16 + hi * 8];
    __builtin_amdgcn_s_setprio(1);
    o = __builtin_amdgcn_mfma_f32_32x32x16_bf16(va0, pb0, o, 0, 0, 0);
    o = __builtin_amdgcn_mfma_f32_32x32x16_bf16(va1, pb1, o, 0, 0, 0);
    __builtin_amdgcn_s_setprio(0);
  }
}

// ---------------- fused MFMA flash attention + merge ----------------
// r12: grid (64, 8); block 1024 = 2 q-waves x 8 z-groups (512 keys each, KVBLK=64).
// LDS 79.9 KB -> 2 blocks/CU = 32 waves/CU = 8 waves/SIMD (needs VGPR<=64, enforced
// by __launch_bounds__(1024,8); staging is kr[2]/vr[2] = half of r11's, which fit 64).
__global__ __launch_bounds__(1024, 8) void attn_fused(
    const unsigned short* __restrict__ Qb, const unsigned short* __restrict__ K2b,
    const unsigned short* __restrict__ Vtb, const float* __restrict__ inp,
    unsigned short* __restrict__ Hbf) {
  __shared__ __align__(16) char smem[77824];   // 8 x (lk[64][40] | lv[32][72]) shorts
  __shared__ float lbuf[8][64];
  const int tid = threadIdx.x;
  const int lane = tid & 63;
  const int wid = tid >> 6;
  const int qw = wid & 1;
  const int zg = wid >> 1;        // 0..7
  const int kl = lane & 31;
  const int hi = lane >> 5;
  const int gtid = tid & 127;
  const int h = blockIdx.y, hc = h * HDIM;
  const int q_local = qw * 32 + kl;
  const int q = blockIdx.x * 64 + q_local;
  const int ks0 = zg * 512;

  short* lk = (short*)smem + zg * 4864;            // [64][40]
  short* lv = (short*)smem + zg * 4864 + 2560;     // [32][72]

  const int kkey = gtid >> 1, kslot = gtid & 1;    // K: 2 thr/key, 2 passes (slots +0,+2)
  const int vdim = gtid >> 3, vslot = gtid & 7;    // V: 16 dims/pass, 2 passes (+16 dims)
  const unsigned short* kg = &K2b[(ks0 + kkey) * DIM + hc + kslot * 8];
  const unsigned short* vg = &Vtb[(hc + vdim) * NN + ks0 + vslot * 8];
  short* lkw = lk + kkey * 40 + kslot * 8;
  short* lvw = lv + vdim * 72 + vslot * 8;

#define LOADKV(KR, VR)                                                      \
  do {                                                                      \
    KR[0] = *(const short8*)(kg);                                           \
    KR[1] = *(const short8*)(kg + 16);                                      \
    VR[0] = *(const short8*)(vg);                                           \
    VR[1] = *(const short8*)(vg + 16 * NN);                                 \
    kg += 64 * DIM; vg += 64;                                               \
  } while (0)
#define STOREKV(KR, VR)                                                     \
  do {                                                                      \
    *(short8*)(lkw) = KR[0];                                                \
    *(short8*)(lkw + 16) = KR[1];                                           \
    *(short8*)(lvw) = VR[0];                                                \
    *(short8*)(lvw + 16 * 72) = VR[1];                                      \
  } while (0)

  short8 qf0 = *(const short8*)&Qb[q * DIM + hc + hi * 8];
  short8 qf1 = *(const short8*)&Qb[q * DIM + hc + 16 + hi * 8];

  f32x16 zc;
#pragma unroll
  for (int r = 0; r < 16; ++r) zc[r] = 0.f;
  f32x16 o = zc;
  float lsum = 0.f;

  short8 kr[2], vr[2];
  LOADKV(kr, vr);
#pragma unroll 1
  for (int t = 0; t < 8; ++t) {
    __syncthreads();                 // all waves done computing previous tile
    STOREKV(kr, vr);                 // (waits on this tile's loads)
    __syncthreads();                 // tile t visible
    if (t < 7) LOADKV(kr, vr);       // issue next tile's loads; land during compute
    compute_tile64(lk, lv, kl, hi, qf0, qf1, zc, o, lsum);
  }
#undef LOADKV
#undef STOREKV

  // in-block merge: o-frags + lsum partials through LDS (aliased over dead K/V tiles)
  float lt = lsum + __shfl_xor(lsum, 32);
  __syncthreads();
  float* mz = (float*)smem + zg * 2208;            // [32 dims][69 q] per group
#pragma unroll
  for (int r = 0; r < 16; ++r) {
    int d = (r & 3) + 8 * (r >> 2) + 4 * hi;
    mz[d * 69 + q_local] = o[r];
  }
  if (hi == 0) lbuf[zg][q_local] = lt;
  __syncthreads();
  if (tid < 512) {
    int ql = tid >> 3;               // 0..63
    int dg = (tid & 7) * 4;          // 0..28
    float s = ((lbuf[0][ql] + lbuf[1][ql]) + (lbuf[2][ql] + lbuf[3][ql])) +
              ((lbuf[4][ql] + lbuf[5][ql]) + (lbuf[6][ql] + lbuf[7][ql]));
    float inv = 1.f / s;
    const float* mb = (const float*)smem;
    float acc[4];
#pragma unroll
    for (int i = 0; i < 4; ++i) {
      int off = (dg + i) * 69 + ql;
      acc[i] = ((mb[off] + mb[2208 + off]) + (mb[4416 + off] + mb[6624 + off])) +
               ((mb[8832 + off] + mb[11040 + off]) +
                (mb[13248 + off] + mb[15456 + off]));
    }
    int qg = blockIdx.x * 64 + ql;
    float4 in4 = *(const float4*)&inp[qg * DIM + hc + dg];
    ushort4 hb;
    hb.x = bfbits(in4.x + acc[0] * inv);
    hb.y = bfbits(in4.y + acc[1] * inv);
    hb.z = bfbits(in4.z + acc[2] * inv);
    hb.w = bfbits(in4.w + acc[3] * inv);
    *(ushort4*)&Hbf[qg * DIM + hc + dg] = hb;
  }
}

// ---------------- final GEMM (bf16 MFMA): out = H + leaky(H @ Wc + bc) ----------------
// Residual H read back from the staged sA tile (bf16) -- no Hf buffer.
__global__ __launch_bounds__(256) void gemm_final_mfma(
    const unsigned short* __restrict__ Hbf, const unsigned short* __restrict__ Wct,
    const float* __restrict__ bc, float* __restrict__ out) {
  __shared__ __align__(16) short sA[64 * 256];
  __shared__ __align__(16) short sB[64 * 256];
  const int tid = threadIdx.x;
  const int m0 = blockIdx.x * 64;
  const int n0 = blockIdx.y * 64;
#pragma unroll
  for (int i = 0; i < 8; ++i) {
    int idx = i * 256 + tid;
    int row = idx >> 5, slot = idx & 31;
    short8 v = *(const short8*)&Hbf[(m0 + row) * DIM + slot * 8];
    int byte = (slot * 16) ^ ((row & 15) << 4);
    *(short8*)((char*)sA + row * 512 + byte) = v;
  }
#pragma unroll
  for (int i = 0; i < 8; ++i) {
    int idx = i * 256 + tid;
    int row = idx >> 5, slot = idx & 31;
    short8 v = *(const short8*)&Wct[(n0 + row) * DIM + slot * 8];
    int byte = (slot * 16) ^ ((row & 15) << 4);
    *(short8*)((char*)sB + row * 512 + byte) = v;
  }
  __syncthreads();
  const int kl = tid & 31, hi = (tid & 63) >> 5, w = tid >> 6;
  const int rw = (w >> 1) * 32, cw = (w & 1) * 32;
  const int arow = rw + kl, brow = cw + kl;
  const int axor = (arow & 15) << 4, bxor = (brow & 15) << 4;
  const char* apA = (const char*)sA + arow * 512;
  const char* apB = (const char*)sB + brow * 512;
  f32x16 acc;
#pragma unroll
  for (int r = 0; r < 16; ++r) acc[r] = 0.f;
#pragma unroll
  for (int ks = 0; ks < 16; ++ks) {
    int cb = ks * 32 + hi * 16;
    short8 a = *(const short8*)(apA + (cb ^ axor));
    short8 b = *(const short8*)(apB + (cb ^ bxor));
    acc = __builtin_amdgcn_mfma_f32_32x32x16_bf16(a, b, acc, 0, 0, 0);
  }
#pragma unroll
  for (int r = 0; r < 16; ++r) {
    int mrow = (r & 3) + 8 * (r >> 2) + 4 * hi;
    int lrow = rw + mrow;
    int node = m0 + lrow, col = n0 + cw + kl;
    float x = acc[r] + bc[col];
    x = x > 0.f ? x : LEAKY * x;
    // residual from staged sA (Hbf tile, swizzle-consistent ushort read)
    unsigned short hr = *(const unsigned short*)(
        (const char*)sA + lrow * 512 + ((col * 2) ^ ((lrow & 15) << 4)));
    out[node * DIM + col] = bf2f(hr) + x;
  }
}

extern "C" void kernel_launch(void* const* d_in, const int* in_sizes, int n_in,
                              void* d_out, int out_size, void* d_ws, size_t ws_size,
                              hipStream_t stream) {
  const float* inp = (const float*)d_in[0];
  const int* src   = (const int*)d_in[1];
  const int* dst   = (const int*)d_in[2];
  const float* WQ  = (const float*)d_in[3];
  const float* WK  = (const float*)d_in[4];
  const float* WV  = (const float*)d_in[5];
  const float* Wc  = (const float*)d_in[6];
  const float* bc  = (const float*)d_in[7];
  float* out = (float*)d_out;
  const int E = in_sizes[1];

  // ws layout (~12.6 MB):
  char* ws = (char*)d_ws;
  unsigned short* Qb  = (unsigned short*)(ws);                      // 2 MB
  unsigned short* Kb  = (unsigned short*)(ws + 2  * 1024 * 1024);   // 2 MB
  unsigned short* Vtb = (unsigned short*)(ws + 4  * 1024 * 1024);   // 2 MB
  unsigned short* K2b = (unsigned short*)(ws + 6  * 1024 * 1024);   // 2 MB
  unsigned short* Wtb = (unsigned short*)(ws + 8  * 1024 * 1024);   // 512 KB
  unsigned short* Hbf = (unsigned short*)(ws + 8 * 1024 * 1024 + 524288);   // 2 MB
  int* cnt            = (int*)(ws + 10 * 1024 * 1024 + 524288);     // 16 KB
  int* esrc           = (int*)(ws + 10 * 1024 * 1024 + 540672);     // 2 MB (4096 x 128)

  const int fillBlocks = (E + 255) / 256;
  convert_w<<<dim3(16, 4), 256, 0, stream>>>(WQ, WK, WV, Wc, Wtb, cnt);
  gemm_fill<<<256 + fillBlocks, 256, 0, stream>>>(inp, Wtb, src, dst, E, cnt, esrc,
                                                  Qb, Kb, Vtb);
  gather_k2<<<NN / 4, 256, 0, stream>>>(Kb, cnt, esrc, K2b);
  attn_fused<<<dim3(64, 8), 1024, 0, stream>>>(Qb, K2b, Vtb, inp, Hbf);
  gemm_final_mfma<<<dim3(64, 4), 256, 0, stream>>>(Hbf, Wtb + 3 * 65536, bc, out);
}

// Round 13
// 239.287 us; speedup vs baseline: 1.3069x; 1.3069x over previous
//
#include <hip/hip_runtime.h>
#include <hip/hip_bf16.h>
#include <math.h>

#define DIM 256
#define HDIM 32
#define NN 4096
#define NM (NN * DIM)
// (1/sqrt(256)) * log2(e) -- folded into WQ so scores are in exp2 domain
#define PREF 0.09016844005555896f
#define LEAKY 0.2f
#define BCAP 128   // edge-bucket capacity per dst (Poisson(32): P(deg>128) ~ 0)

typedef __attribute__((ext_vector_type(8))) short short8;
typedef __attribute__((ext_vector_type(16))) float f32x16;

#if __has_builtin(__builtin_amdgcn_exp2f)
#define EXP2(x) __builtin_amdgcn_exp2f(x)   // raw v_exp_f32: scores bounded, no fixups needed
#else
#define EXP2(x) exp2f(x)
#endif

static __device__ __forceinline__ unsigned bfbits(float x) {
  unsigned u = __float_as_uint(x);
  return (u + 0x7fffu + ((u >> 16) & 1u)) >> 16;   // RNE f32->bf16 bits
}
static __device__ __forceinline__ float bf2f(unsigned short b) {
  return __uint_as_float(((unsigned)b) << 16);
}
static __device__ __forceinline__ unsigned pk_bf16(float lo, float hi) {
  __hip_bfloat162 t = __float22bfloat162_rn(make_float2(lo, hi));  // v_cvt_pk_bf16_f32
  return *(unsigned*)&t;
}

// ---- convert: Wtb[w][n][k] = bf16(W_w[k][n]*scale); grid (16,4); y==0 blocks zero cnt
__global__ __launch_bounds__(256) void convert_w(
    const float* __restrict__ W0, const float* __restrict__ W1,
    const float* __restrict__ W2, const float* __restrict__ W3,
    unsigned short* __restrict__ Wtb, int* __restrict__ cnt) {
  const int tid = threadIdx.x;
  if (blockIdx.y == 0) cnt[blockIdx.x * 256 + tid] = 0;   // 16x256 = 4096 ints
  __shared__ float tile[64][68];
  const int wsel = blockIdx.y;
  const float* W = wsel == 0 ? W0 : (wsel == 1 ? W1 : (wsel == 2 ? W2 : W3));
  const float scale = wsel == 0 ? PREF : 1.f;
  const int kb = (blockIdx.x & 3) * 64, nb = (blockIdx.x >> 2) * 64;
#pragma unroll
  for (int i = 0; i < 4; ++i) {
    int idx = i * 256 + tid;
    int kr = idx >> 4, ns = idx & 15;
    float4 v = *(const float4*)&W[(kb + kr) * DIM + nb + ns * 4];
    tile[kr][ns * 4 + 0] = v.x; tile[kr][ns * 4 + 1] = v.y;
    tile[kr][ns * 4 + 2] = v.z; tile[kr][ns * 4 + 3] = v.w;
  }
  __syncthreads();
  unsigned short* o = Wtb + wsel * 65536;
#pragma unroll
  for (int i = 0; i < 2; ++i) {
    int idx = i * 256 + tid;
    int nr = idx >> 3, kslot = idx & 7;
    short8 v;
#pragma unroll
    for (int j = 0; j < 8; ++j)
      ((unsigned short*)&v)[j] = (unsigned short)bfbits(tile[kslot * 8 + j][nr] * scale);
    *(short8*)&o[(nb + nr) * DIM + kb + kslot * 8] = v;
  }
}

// ---------------- fused: QKV GEMM (blocks 0..255) + edge-bucket fill (blocks 256+) ----
__global__ __launch_bounds__(256) void gemm_fill(
    const float* __restrict__ inp, const unsigned short* __restrict__ Wtb,
    const int* __restrict__ src, const int* __restrict__ dst, int E,
    int* __restrict__ cnt, int* __restrict__ esrc,
    unsigned short* __restrict__ Qb, unsigned short* __restrict__ Kb,
    unsigned short* __restrict__ Vtb) {
  __shared__ __align__(16) short sA[64 * 256];   // 32 KB
  __shared__ __align__(16) short sB[64 * 256];   // 32 KB
  const int tid = threadIdx.x;
  const int b = blockIdx.x;
  if (b >= 256) {                  // fill: slot = atomicAdd(cnt[d]); esrc[d*BCAP+slot]=src
    int e = (b - 256) * 256 + tid;
    if (e < E) {
      int d = dst[e];
      int p = atomicAdd(&cnt[d], 1);
      if (p < BCAP) esrc[d * BCAP + p] = src[e];
    }
    return;
  }
  const int m0 = (b & 63) * 64;
  const int n0 = (b >> 6) * 64;
  // stage A once: f32 -> bf16 during copy (64 rows x 64 slots x 4 f32)
#pragma unroll
  for (int i = 0; i < 16; ++i) {
    int idx = i * 256 + tid;
    int row = idx >> 6, slot = idx & 63;
    float4 v = *(const float4*)&inp[(m0 + row) * DIM + slot * 4];
    uint2 pk = make_uint2(pk_bf16(v.x, v.y), pk_bf16(v.z, v.w));
    int byte = (slot * 8) ^ ((row & 15) << 4);
    *(uint2*)((char*)sA + row * 512 + byte) = pk;
  }
  const int kl = tid & 31, hi = (tid & 63) >> 5, w = tid >> 6;
  const int rw = (w >> 1) * 32, cw = (w & 1) * 32;
  const int arow = rw + kl, brow = cw + kl;
  const int axor = (arow & 15) << 4, bxor = (brow & 15) << 4;
  const char* apA = (const char*)sA + arow * 512;
  const char* apB = (const char*)sB + brow * 512;

#pragma unroll 1
  for (int wsel = 0; wsel < 3; ++wsel) {
    const unsigned short* Wt = Wtb + wsel * 65536;
    __syncthreads();               // prev compute done reading sB (wsel0: none)
#pragma unroll
    for (int i = 0; i < 8; ++i) {
      int idx = i * 256 + tid;
      int row = idx >> 5, slot = idx & 31;
      short8 v = *(const short8*)&Wt[(n0 + row) * DIM + slot * 8];
      int byte = (slot * 16) ^ ((row & 15) << 4);
      *(short8*)((char*)sB + row * 512 + byte) = v;
    }
    __syncthreads();               // sB (and sA on first iter) visible
    f32x16 acc;
#pragma unroll
    for (int r = 0; r < 16; ++r) acc[r] = 0.f;
#pragma unroll
    for (int ks = 0; ks < 16; ++ks) {
      int cb = ks * 32 + hi * 16;
      short8 a = *(const short8*)(apA + (cb ^ axor));
      short8 bfr = *(const short8*)(apB + (cb ^ bxor));
      acc = __builtin_amdgcn_mfma_f32_32x32x16_bf16(a, bfr, acc, 0, 0, 0);
    }
    if (wsel < 2) {
      unsigned short* C = wsel == 0 ? Qb : Kb;
#pragma unroll
      for (int r = 0; r < 16; ++r) {
        int mrow = (r & 3) + 8 * (r >> 2) + 4 * hi;
        C[(m0 + rw + mrow) * DIM + n0 + cw + kl] = (unsigned short)bfbits(acc[r]);
      }
    } else {
      // V: transpose via LDS (sB reused as [64 m][72] ushort tile) -> Vtb[dim][node]
      __syncthreads();             // all waves done reading sB
      unsigned short* tile = (unsigned short*)sB;
#pragma unroll
      for (int r = 0; r < 16; ++r) {
        int mrow = (r & 3) + 8 * (r >> 2) + 4 * hi;
        tile[(rw + mrow) * 72 + cw + kl] = (unsigned short)bfbits(acc[r]);
      }
      __syncthreads();
#pragma unroll
      for (int i = 0; i < 2; ++i) {
        int idx = i * 256 + tid;
        int drow = idx >> 3, nslot = idx & 7;
        short8 v;
#pragma unroll
        for (int j = 0; j < 8; ++j)
          ((unsigned short*)&v)[j] = tile[(nslot * 8 + j) * 72 + drow];
        *(short8*)&Vtb[(n0 + drow) * NN + m0 + nslot * 8] = v;
      }
    }
  }
}

// ---------------- K2 gather from buckets: wave per dst node, ILP-4 ----------------
__global__ __launch_bounds__(256) void gather_k2(
    const unsigned short* __restrict__ Kb, const int* __restrict__ cnt,
    const int* __restrict__ esrc, unsigned short* __restrict__ K2b) {
  int w = threadIdx.x >> 6, lane = threadIdx.x & 63;
  int d = blockIdx.x * 4 + w;
  int n = cnt[d]; n = n > BCAP ? BCAP : n;
  const int* eb = esrc + d * BCAP;
  float a0 = 0, a1 = 0, a2 = 0, a3 = 0;
  int j = 0;
  for (; j + 4 <= n; j += 4) {     // 4 independent load chains in flight
    int s0 = eb[j], s1 = eb[j + 1], s2 = eb[j + 2], s3 = eb[j + 3];
    ushort4 k0 = *(const ushort4*)&Kb[s0 * DIM + lane * 4];
    ushort4 k1 = *(const ushort4*)&Kb[s1 * DIM + lane * 4];
    ushort4 k2 = *(const ushort4*)&Kb[s2 * DIM + lane * 4];
    ushort4 k3 = *(const ushort4*)&Kb[s3 * DIM + lane * 4];
    a0 += bf2f(k0.x) + bf2f(k1.x) + bf2f(k2.x) + bf2f(k3.x);
    a1 += bf2f(k0.y) + bf2f(k1.y) + bf2f(k2.y) + bf2f(k3.y);
    a2 += bf2f(k0.z) + bf2f(k1.z) + bf2f(k2.z) + bf2f(k3.z);
    a3 += bf2f(k0.w) + bf2f(k1.w) + bf2f(k2.w) + bf2f(k3.w);
  }
  for (; j < n; ++j) {
    int s = eb[j];
    ushort4 kv = *(const ushort4*)&Kb[s * DIM + lane * 4];
    a0 += bf2f(kv.x); a1 += bf2f(kv.y); a2 += bf2f(kv.z); a3 += bf2f(kv.w);
  }
  ushort4 o;
  o.x = bfbits(a0); o.y = bfbits(a1); o.z = bfbits(a2); o.w = bfbits(a3);
  *(ushort4*)&K2b[d * DIM + lane * 4] = o;
}

// ---- per-tile compute (64-key tile, 2 subs): QK^T -> exp2 -> pack/permlane -> PV ----
static __device__ __forceinline__ void compute_tile64(
    const short* __restrict__ lk, const short* __restrict__ lv, int kl, int hi,
    short8 qf0, short8 qf1, const f32x16& zc, f32x16& o, float& lsum) {
#pragma unroll
  for (int sub = 0; sub < 2; ++sub) {
    const int base = sub * 32;
    short8 a0 = *(const short8*)&lk[(base + kl) * 40 + hi * 8];
    short8 a1 = *(const short8*)&lk[(base + kl) * 40 + 16 + hi * 8];
    __builtin_amdgcn_s_setprio(1);
    f32x16 c = __builtin_amdgcn_mfma_f32_32x32x16_bf16(a0, qf0, zc, 0, 0, 0);
    c = __builtin_amdgcn_mfma_f32_32x32x16_bf16(a1, qf1, c, 0, 0, 0);
    __builtin_amdgcn_s_setprio(0);
    float p[16];
#pragma unroll
    for (int r = 0; r < 16; ++r) p[r] = EXP2(c[r]);
    {  // scalar tree-sum
      float t0 = (p[0] + p[1]) + (p[2] + p[3]);
      float t1 = (p[4] + p[5]) + (p[6] + p[7]);
      float t2 = (p[8] + p[9]) + (p[10] + p[11]);
      float t3 = (p[12] + p[13]) + (p[14] + p[15]);
      lsum += (t0 + t1) + (t2 + t3);
    }
    unsigned X0 = pk_bf16(p[0], p[1]);
    unsigned Y0 = pk_bf16(p[2], p[3]);
    unsigned Z0 = pk_bf16(p[4], p[5]);
    unsigned W0 = pk_bf16(p[6], p[7]);
    asm volatile("v_permlane32_swap_b32 %0, %1" : "+v"(X0), "+v"(Z0));
    asm volatile("v_permlane32_swap_b32 %0, %1" : "+v"(Y0), "+v"(W0));
    unsigned X1 = pk_bf16(p[8], p[9]);
    unsigned Y1 = pk_bf16(p[10], p[11]);
    unsigned Z1 = pk_bf16(p[12], p[13]);
    unsigned W1 = pk_bf16(p[14], p[15]);
    asm volatile("v_permlane32_swap_b32 %0, %1" : "+v"(X1), "+v"(Z1));
    asm volatile("v_permlane32_swap_b32 %0, %1" : "+v"(Y1), "+v"(W1));
    short8 pb0, pb1;
    ((unsigned*)&pb0)[0] = X0; ((unsigned*)&pb0)[1] = Y0;
    ((unsigned*)&pb0)[2] = Z0; ((unsigned*)&pb0)[3] = W0;
    ((unsigned*)&pb1)[0] = X1; ((unsigned*)&pb1)[1] = Y1;
    ((unsigned*)&pb1)[2] = Z1; ((unsigned*)&pb1)[3] = W1;
    short8 va0 = *(const short8*)&lv[kl * 72 + base + hi * 8];
    short8 va1 = *(const short8*)&lv[kl * 72 + base + 16 + hi * 8];
    __builtin_amdgcn_s_setprio(1);
    o = __builtin_amdgcn_mfma_f32_32x32x16_bf16(va0, pb0, o, 0, 0, 0);
    o = __builtin_amdgcn_mfma_f32_32x32x16_bf16(va1, pb1, o, 0, 0, 0);
    __builtin_amdgcn_s_setprio(0);
  }
}

// ---------------- fused MFMA flash attention + merge ----------------
// r13: grid (64, 8); block 512 = 2 q-waves x 4 z-groups, KVBLK=64 x 16 tiles.
// LDS 39.9 KB -> 3 blocks/CU = 24 waves/CU = 6 waves/SIMD. launch_bounds(512,6)
// caps regs at ~84 (r11's equivalent compiled to 64 naturally -- headroom, no spill;
// r12's (1024,8) cap of 64 total caused the 808MB spill storm).
__global__ __launch_bounds__(512, 6) void attn_fused(
    const unsigned short* __restrict__ Qb, const unsigned short* __restrict__ K2b,
    const unsigned short* __restrict__ Vtb, const float* __restrict__ inp,
    unsigned short* __restrict__ Hbf) {
  __shared__ __align__(16) char smem[38912];   // 4 x (lk[64][40] | lv[32][72]) shorts
  __shared__ float lbuf[4][64];
  const int tid = threadIdx.x;
  const int lane = tid & 63;
  const int wid = tid >> 6;
  const int qw = wid & 1;
  const int zg = wid >> 1;        // 0..3
  const int kl = lane & 31;
  const int hi = lane >> 5;
  const int gtid = tid & 127;
  const int h = blockIdx.y, hc = h * HDIM;
  const int q_local = qw * 32 + kl;
  const int q = blockIdx.x * 64 + q_local;
  const int ks0 = zg * 1024;

  short* lk = (short*)smem + zg * 4864;            // [64][40]
  short* lv = (short*)smem + zg * 4864 + 2560;     // [32][72]

  const int kkey = gtid >> 1, kslot = gtid & 1;    // K: 2 thr/key, slots {0,1}+{2,3}
  const int vdim = gtid >> 3, vslot = gtid & 7;    // V: dims vdim, vdim+16
  const unsigned short* kg = &K2b[(ks0 + kkey) * DIM + hc + kslot * 16];
  const unsigned short* vg = &Vtb[(hc + vdim) * NN + ks0 + vslot * 8];
  short* lkw = lk + kkey * 40 + kslot * 16;
  short* lvw = lv + vdim * 72 + vslot * 8;

#define LOADKV(KR, VR)                                                      \
  do {                                                                      \
    KR[0] = *(const short8*)(kg);                                           \
    KR[1] = *(const short8*)(kg + 8);                                       \
    VR[0] = *(const short8*)(vg);                                           \
    VR[1] = *(const short8*)(vg + 16 * NN);                                 \
    kg += 64 * DIM; vg += 64;                                               \
  } while (0)
#define STOREKV(KR, VR)                                                     \
  do {                                                                      \
    *(short8*)(lkw) = KR[0];                                                \
    *(short8*)(lkw + 8) = KR[1];                                            \
    *(short8*)(lvw) = VR[0];                                                \
    *(short8*)(lvw + 16 * 72) = VR[1];                                      \
  } while (0)

  short8 qf0 = *(const short8*)&Qb[q * DIM + hc + hi * 8];
  short8 qf1 = *(const short8*)&Qb[q * DIM + hc + 16 + hi * 8];

  f32x16 zc;
#pragma unroll
  for (int r = 0; r < 16; ++r) zc[r] = 0.f;
  f32x16 o = zc;
  float lsum = 0.f;

  short8 kr[2], vr[2];
  LOADKV(kr, vr);
#pragma unroll 1
  for (int t = 0; t < 16; ++t) {
    __syncthreads();                 // all waves done computing previous tile
    STOREKV(kr, vr);                 // (waits on this tile's loads)
    __syncthreads();                 // tile t visible
    if (t < 15) LOADKV(kr, vr);      // issue next tile's loads; land during compute
    compute_tile64(lk, lv, kl, hi, qf0, qf1, zc, o, lsum);
  }
#undef LOADKV
#undef STOREKV

  // in-block merge: o-frags + lsum partials through LDS (aliased over dead K/V tiles)
  float lt = lsum + __shfl_xor(lsum, 32);
  __syncthreads();
  float* mz = (float*)smem + zg * 2208;            // [32 dims][69 q] per group
#pragma unroll
  for (int r = 0; r < 16; ++r) {
    int d = (r & 3) + 8 * (r >> 2) + 4 * hi;
    mz[d * 69 + q_local] = o[r];
  }
  if (hi == 0) lbuf[zg][q_local] = lt;
  __syncthreads();
  {
    int ql = tid >> 3;               // 0..63
    int dg = (tid & 7) * 4;          // 0..28
    float s = (lbuf[0][ql] + lbuf[1][ql]) + (lbuf[2][ql] + lbuf[3][ql]);
    float inv = 1.f / s;
    const float* mb = (const float*)smem;
    float acc[4];
#pragma unroll
    for (int i = 0; i < 4; ++i) {
      int off = (dg + i) * 69 + ql;
      acc[i] = (mb[off] + mb[2208 + off]) + (mb[4416 + off] + mb[6624 + off]);
    }
    int qg = blockIdx.x * 64 + ql;
    float4 in4 = *(const float4*)&inp[qg * DIM + hc + dg];
    ushort4 hb;
    hb.x = bfbits(in4.x + acc[0] * inv);
    hb.y = bfbits(in4.y + acc[1] * inv);
    hb.z = bfbits(in4.z + acc[2] * inv);
    hb.w = bfbits(in4.w + acc[3] * inv);
    *(ushort4*)&Hbf[qg * DIM + hc + dg] = hb;
  }
}

// ---------------- final GEMM (bf16 MFMA): out = H + leaky(H @ Wc + bc) ----------------
// Residual H read back from the staged sA tile (bf16) -- no Hf buffer.
__global__ __launch_bounds__(256) void gemm_final_mfma(
    const unsigned short* __restrict__ Hbf, const unsigned short* __restrict__ Wct,
    const float* __restrict__ bc, float* __restrict__ out) {
  __shared__ __align__(16) short sA[64 * 256];
  __shared__ __align__(16) short sB[64 * 256];
  const int tid = threadIdx.x;
  const int m0 = blockIdx.x * 64;
  const int n0 = blockIdx.y * 64;
#pragma unroll
  for (int i = 0; i < 8; ++i) {
    int idx = i * 256 + tid;
    int row = idx >> 5, slot = idx & 31;
    short8 v = *(const short8*)&Hbf[(m0 + row) * DIM + slot * 8];
    int byte = (slot * 16) ^ ((row & 15) << 4);
    *(short8*)((char*)sA + row * 512 + byte) = v;
  }
#pragma unroll
  for (int i = 0; i < 8; ++i) {
    int idx = i * 256 + tid;
    int row = idx >> 5, slot = idx & 31;
    short8 v = *(const short8*)&Wct[(n0 + row) * DIM + slot * 8];
    int byte = (slot * 16) ^ ((row & 15) << 4);
    *(short8*)((char*)sB + row * 512 + byte) = v;
  }
  __syncthreads();
  const int kl = tid & 31, hi = (tid & 63) >> 5, w = tid >> 6;
  const int rw = (w >> 1) * 32, cw = (w & 1) * 32;
  const int arow = rw + kl, brow = cw + kl;
  const int axor = (arow & 15) << 4, bxor = (brow & 15) << 4;
  const char* apA = (const char*)sA + arow * 512;
  const char* apB = (const char*)sB + brow * 512;
  f32x16 acc;
#pragma unroll
  for (int r = 0; r < 16; ++r) acc[r] = 0.f;
#pragma unroll
  for (int ks = 0; ks < 16; ++ks) {
    int cb = ks * 32 + hi * 16;
    short8 a = *(const short8*)(apA + (cb ^ axor));
    short8 b = *(const short8*)(apB + (cb ^ bxor));
    acc = __builtin_amdgcn_mfma_f32_32x32x16_bf16(a, b, acc, 0, 0, 0);
  }
#pragma unroll
  for (int r = 0; r < 16; ++r) {
    int mrow = (r & 3) + 8 * (r >> 2) + 4 * hi;
    int lrow = rw + mrow;
    int node = m0 + lrow, col = n0 + cw + kl;
    float x = acc[r] + bc[col];
    x = x > 0.f ? x : LEAKY * x;
    // residual from staged sA (Hbf tile, swizzle-consistent ushort read)
    unsigned short hr = *(const unsigned short*)(
        (const char*)sA + lrow * 512 + ((col * 2) ^ ((lrow & 15) << 4)));
    out[node * DIM + col] = bf2f(hr) + x;
  }
}

extern "C" void kernel_launch(void* const* d_in, const int* in_sizes, int n_in,
                              void* d_out, int out_size, void* d_ws, size_t ws_size,
                              hipStream_t stream) {
  const float* inp = (const float*)d_in[0];
  const int* src   = (const int*)d_in[1];
  const int* dst   = (const int*)d_in[2];
  const float* WQ  = (const float*)d_in[3];
  const float* WK  = (const float*)d_in[4];
  const float* WV  = (const float*)d_in[5];
  const float* Wc  = (const float*)d_in[6];
  const float* bc  = (const float*)d_in[7];
  float* out = (float*)d_out;
  const int E = in_sizes[1];

  // ws layout (~12.6 MB):
  char* ws = (char*)d_ws;
  unsigned short* Qb  = (unsigned short*)(ws);                      // 2 MB
  unsigned short* Kb  = (unsigned short*)(ws + 2  * 1024 * 1024);   // 2 MB
  unsigned short* Vtb = (unsigned short*)(ws + 4  * 1024 * 1024);   // 2 MB
  unsigned short* K2b = (unsigned short*)(ws + 6  * 1024 * 1024);   // 2 MB
  unsigned short* Wtb = (unsigned short*)(ws + 8  * 1024 * 1024);   // 512 KB
  unsigned short* Hbf = (unsigned short*)(ws + 8 * 1024 * 1024 + 524288);   // 2 MB
  int* cnt            = (int*)(ws + 10 * 1024 * 1024 + 524288);     // 16 KB
  int* esrc           = (int*)(ws + 10 * 1024 * 1024 + 540672);     // 2 MB (4096 x 128)

  const int fillBlocks = (E + 255) / 256;
  convert_w<<<dim3(16, 4), 256, 0, stream>>>(WQ, WK, WV, Wc, Wtb, cnt);
  gemm_fill<<<256 + fillBlocks, 256, 0, stream>>>(inp, Wtb, src, dst, E, cnt, esrc,
                                                  Qb, Kb, Vtb);
  gather_k2<<<NN / 4, 256, 0, stream>>>(Kb, cnt, esrc, K2b);
  attn_fused<<<dim3(64, 8), 512, 0, stream>>>(Qb, K2b, Vtb, inp, Hbf);
  gemm_final_mfma<<<dim3(64, 4), 256, 0, stream>>>(Hbf, Wtb + 3 * 65536, bc, out);
}

// Round 14
// 75.647 us; speedup vs baseline: 4.1340x; 3.1632x over previous
//
#include <hip/hip_runtime.h>
#include <hip/hip_bf16.h>
#include <math.h>

#define DIM 256
#define HDIM 32
#define NN 4096
#define NM (NN * DIM)
// (1/sqrt(256)) * log2(e) -- folded into WQ so scores are in exp2 domain
#define PREF 0.09016844005555896f
#define LEAKY 0.2f
#define BCAP 128   // edge-bucket capacity per dst (Poisson(32): P(deg>128) ~ 0)

typedef __attribute__((ext_vector_type(8))) short short8;
typedef __attribute__((ext_vector_type(16))) float f32x16;

#if __has_builtin(__builtin_amdgcn_exp2f)
#define EXP2(x) __builtin_amdgcn_exp2f(x)   // raw v_exp_f32: scores bounded, no fixups needed
#else
#define EXP2(x) exp2f(x)
#endif

static __device__ __forceinline__ unsigned bfbits(float x) {
  unsigned u = __float_as_uint(x);
  return (u + 0x7fffu + ((u >> 16) & 1u)) >> 16;   // RNE f32->bf16 bits
}
static __device__ __forceinline__ float bf2f(unsigned short b) {
  return __uint_as_float(((unsigned)b) << 16);
}
static __device__ __forceinline__ unsigned pk_bf16(float lo, float hi) {
  __hip_bfloat162 t = __float22bfloat162_rn(make_float2(lo, hi));  // v_cvt_pk_bf16_f32
  return *(unsigned*)&t;
}

// ---- convert: Wtb[w][n][k] = bf16(W_w[k][n]*scale); grid (16,4); y==0 blocks zero cnt
__global__ __launch_bounds__(256) void convert_w(
    const float* __restrict__ W0, const float* __restrict__ W1,
    const float* __restrict__ W2, const float* __restrict__ W3,
    unsigned short* __restrict__ Wtb, int* __restrict__ cnt) {
  const int tid = threadIdx.x;
  if (blockIdx.y == 0) cnt[blockIdx.x * 256 + tid] = 0;   // 16x256 = 4096 ints
  __shared__ float tile[64][68];
  const int wsel = blockIdx.y;
  const float* W = wsel == 0 ? W0 : (wsel == 1 ? W1 : (wsel == 2 ? W2 : W3));
  const float scale = wsel == 0 ? PREF : 1.f;
  const int kb = (blockIdx.x & 3) * 64, nb = (blockIdx.x >> 2) * 64;
#pragma unroll
  for (int i = 0; i < 4; ++i) {
    int idx = i * 256 + tid;
    int kr = idx >> 4, ns = idx & 15;
    float4 v = *(const float4*)&W[(kb + kr) * DIM + nb + ns * 4];
    tile[kr][ns * 4 + 0] = v.x; tile[kr][ns * 4 + 1] = v.y;
    tile[kr][ns * 4 + 2] = v.z; tile[kr][ns * 4 + 3] = v.w;
  }
  __syncthreads();
  unsigned short* o = Wtb + wsel * 65536;
#pragma unroll
  for (int i = 0; i < 2; ++i) {
    int idx = i * 256 + tid;
    int nr = idx >> 3, kslot = idx & 7;
    short8 v;
#pragma unroll
    for (int j = 0; j < 8; ++j)
      ((unsigned short*)&v)[j] = (unsigned short)bfbits(tile[kslot * 8 + j][nr] * scale);
    *(short8*)&o[(nb + nr) * DIM + kb + kslot * 8] = v;
  }
}

// ---------------- fused: QKV GEMM (blocks 0..255) + edge-bucket fill (blocks 256+) ----
__global__ __launch_bounds__(256) void gemm_fill(
    const float* __restrict__ inp, const unsigned short* __restrict__ Wtb,
    const int* __restrict__ src, const int* __restrict__ dst, int E,
    int* __restrict__ cnt, int* __restrict__ esrc,
    unsigned short* __restrict__ Qb, unsigned short* __restrict__ Kb,
    unsigned short* __restrict__ Vtb) {
  __shared__ __align__(16) short sA[64 * 256];   // 32 KB
  __shared__ __align__(16) short sB[64 * 256];   // 32 KB
  const int tid = threadIdx.x;
  const int b = blockIdx.x;
  if (b >= 256) {                  // fill: slot = atomicAdd(cnt[d]); esrc[d*BCAP+slot]=src
    int e = (b - 256) * 256 + tid;
    if (e < E) {
      int d = dst[e];
      int p = atomicAdd(&cnt[d], 1);
      if (p < BCAP) esrc[d * BCAP + p] = src[e];
    }
    return;
  }
  const int m0 = (b & 63) * 64;
  const int n0 = (b >> 6) * 64;
  // stage A once: f32 -> bf16 during copy (64 rows x 64 slots x 4 f32)
#pragma unroll
  for (int i = 0; i < 16; ++i) {
    int idx = i * 256 + tid;
    int row = idx >> 6, slot = idx & 63;
    float4 v = *(const float4*)&inp[(m0 + row) * DIM + slot * 4];
    uint2 pk = make_uint2(pk_bf16(v.x, v.y), pk_bf16(v.z, v.w));
    int byte = (slot * 8) ^ ((row & 15) << 4);
    *(uint2*)((char*)sA + row * 512 + byte) = pk;
  }
  const int kl = tid & 31, hi = (tid & 63) >> 5, w = tid >> 6;
  const int rw = (w >> 1) * 32, cw = (w & 1) * 32;
  const int arow = rw + kl, brow = cw + kl;
  const int axor = (arow & 15) << 4, bxor = (brow & 15) << 4;
  const char* apA = (const char*)sA + arow * 512;
  const char* apB = (const char*)sB + brow * 512;

#pragma unroll 1
  for (int wsel = 0; wsel < 3; ++wsel) {
    const unsigned short* Wt = Wtb + wsel * 65536;
    __syncthreads();               // prev compute done reading sB (wsel0: none)
#pragma unroll
    for (int i = 0; i < 8; ++i) {
      int idx = i * 256 + tid;
      int row = idx >> 5, slot = idx & 31;
      short8 v = *(const short8*)&Wt[(n0 + row) * DIM + slot * 8];
      int byte = (slot * 16) ^ ((row & 15) << 4);
      *(short8*)((char*)sB + row * 512 + byte) = v;
    }
    __syncthreads();               // sB (and sA on first iter) visible
    f32x16 acc;
#pragma unroll
    for (int r = 0; r < 16; ++r) acc[r] = 0.f;
#pragma unroll
    for (int ks = 0; ks < 16; ++ks) {
      int cb = ks * 32 + hi * 16;
      short8 a = *(const short8*)(apA + (cb ^ axor));
      short8 bfr = *(const short8*)(apB + (cb ^ bxor));
      acc = __builtin_amdgcn_mfma_f32_32x32x16_bf16(a, bfr, acc, 0, 0, 0);
    }
    if (wsel < 2) {
      unsigned short* C = wsel == 0 ? Qb : Kb;
#pragma unroll
      for (int r = 0; r < 16; ++r) {
        int mrow = (r & 3) + 8 * (r >> 2) + 4 * hi;
        C[(m0 + rw + mrow) * DIM + n0 + cw + kl] = (unsigned short)bfbits(acc[r]);
      }
    } else {
      // V: transpose via LDS (sB reused as [64 m][72] ushort tile) -> Vtb[dim][node]
      __syncthreads();             // all waves done reading sB
      unsigned short* tile = (unsigned short*)sB;
#pragma unroll
      for (int r = 0; r < 16; ++r) {
        int mrow = (r & 3) + 8 * (r >> 2) + 4 * hi;
        tile[(rw + mrow) * 72 + cw + kl] = (unsigned short)bfbits(acc[r]);
      }
      __syncthreads();
#pragma unroll
      for (int i = 0; i < 2; ++i) {
        int idx = i * 256 + tid;
        int drow = idx >> 3, nslot = idx & 7;
        short8 v;
#pragma unroll
        for (int j = 0; j < 8; ++j)
          ((unsigned short*)&v)[j] = tile[(nslot * 8 + j) * 72 + drow];
        *(short8*)&Vtb[(n0 + drow) * NN + m0 + nslot * 8] = v;
      }
    }
  }
}

// ---------------- K2 gather from buckets: wave per dst node, ILP-4 ----------------
__global__ __launch_bounds__(256) void gather_k2(
    const unsigned short* __restrict__ Kb, const int* __restrict__ cnt,
    const int* __restrict__ esrc, unsigned short* __restrict__ K2b) {
  int w = threadIdx.x >> 6, lane = threadIdx.x & 63;
  int d = blockIdx.x * 4 + w;
  int n = cnt[d]; n = n > BCAP ? BCAP : n;
  const int* eb = esrc + d * BCAP;
  float a0 = 0, a1 = 0, a2 = 0, a3 = 0;
  int j = 0;
  for (; j + 4 <= n; j += 4) {     // 4 independent load chains in flight
    int s0 = eb[j], s1 = eb[j + 1], s2 = eb[j + 2], s3 = eb[j + 3];
    ushort4 k0 = *(const ushort4*)&Kb[s0 * DIM + lane * 4];
    ushort4 k1 = *(const ushort4*)&Kb[s1 * DIM + lane * 4];
    ushort4 k2 = *(const ushort4*)&Kb[s2 * DIM + lane * 4];
    ushort4 k3 = *(const ushort4*)&Kb[s3 * DIM + lane * 4];
    a0 += bf2f(k0.x) + bf2f(k1.x) + bf2f(k2.x) + bf2f(k3.x);
    a1 += bf2f(k0.y) + bf2f(k1.y) + bf2f(k2.y) + bf2f(k3.y);
    a2 += bf2f(k0.z) + bf2f(k1.z) + bf2f(k2.z) + bf2f(k3.z);
    a3 += bf2f(k0.w) + bf2f(k1.w) + bf2f(k2.w) + bf2f(k3.w);
  }
  for (; j < n; ++j) {
    int s = eb[j];
    ushort4 kv = *(const ushort4*)&Kb[s * DIM + lane * 4];
    a0 += bf2f(kv.x); a1 += bf2f(kv.y); a2 += bf2f(kv.z); a3 += bf2f(kv.w);
  }
  ushort4 o;
  o.x = bfbits(a0); o.y = bfbits(a1); o.z = bfbits(a2); o.w = bfbits(a3);
  *(ushort4*)&K2b[d * DIM + lane * 4] = o;
}

// ---- per-tile compute (64-key tile, 2 subs): QK^T -> exp2 -> pack/permlane -> PV ----
static __device__ __forceinline__ void compute_tile64(
    const short* __restrict__ lk, const short* __restrict__ lv, int kl, int hi,
    short8 qf0, short8 qf1, const f32x16& zc, f32x16& o, float& lsum) {
#pragma unroll
  for (int sub = 0; sub < 2; ++sub) {
    const int base = sub * 32;
    short8 a0 = *(const short8*)&lk[(base + kl) * 40 + hi * 8];
    short8 a1 = *(const short8*)&lk[(base + kl) * 40 + 16 + hi * 8];
    __builtin_amdgcn_s_setprio(1);
    f32x16 c = __builtin_amdgcn_mfma_f32_32x32x16_bf16(a0, qf0, zc, 0, 0, 0);
    c = __builtin_amdgcn_mfma_f32_32x32x16_bf16(a1, qf1, c, 0, 0, 0);
    __builtin_amdgcn_s_setprio(0);
    float p[16];
#pragma unroll
    for (int r = 0; r < 16; ++r) p[r] = EXP2(c[r]);
    {  // scalar tree-sum
      float t0 = (p[0] + p[1]) + (p[2] + p[3]);
      float t1 = (p[4] + p[5]) + (p[6] + p[7]);
      float t2 = (p[8] + p[9]) + (p[10] + p[11]);
      float t3 = (p[12] + p[13]) + (p[14] + p[15]);
      lsum += (t0 + t1) + (t2 + t3);
    }
    unsigned X0 = pk_bf16(p[0], p[1]);
    unsigned Y0 = pk_bf16(p[2], p[3]);
    unsigned Z0 = pk_bf16(p[4], p[5]);
    unsigned W0 = pk_bf16(p[6], p[7]);
    asm volatile("v_permlane32_swap_b32 %0, %1" : "+v"(X0), "+v"(Z0));
    asm volatile("v_permlane32_swap_b32 %0, %1" : "+v"(Y0), "+v"(W0));
    unsigned X1 = pk_bf16(p[8], p[9]);
    unsigned Y1 = pk_bf16(p[10], p[11]);
    unsigned Z1 = pk_bf16(p[12], p[13]);
    unsigned W1 = pk_bf16(p[14], p[15]);
    asm volatile("v_permlane32_swap_b32 %0, %1" : "+v"(X1), "+v"(Z1));
    asm volatile("v_permlane32_swap_b32 %0, %1" : "+v"(Y1), "+v"(W1));
    short8 pb0, pb1;
    ((unsigned*)&pb0)[0] = X0; ((unsigned*)&pb0)[1] = Y0;
    ((unsigned*)&pb0)[2] = Z0; ((unsigned*)&pb0)[3] = W0;
    ((unsigned*)&pb1)[0] = X1; ((unsigned*)&pb1)[1] = Y1;
    ((unsigned*)&pb1)[2] = Z1; ((unsigned*)&pb1)[3] = W1;
    short8 va0 = *(const short8*)&lv[kl * 72 + base + hi * 8];
    short8 va1 = *(const short8*)&lv[kl * 72 + base + 16 + hi * 8];
    __builtin_amdgcn_s_setprio(1);
    o = __builtin_amdgcn_mfma_f32_32x32x16_bf16(va0, pb0, o, 0, 0, 0);
    o = __builtin_amdgcn_mfma_f32_32x32x16_bf16(va1, pb1, o, 0, 0, 0);
    __builtin_amdgcn_s_setprio(0);
  }
}

// ---------------- fused MFMA flash attention + merge ----------------
// r14: grid (64, 8); block 512 = 2 q-waves x 4 z-groups, KVBLK=64 x 16 tiles.
// LDS 39.9 KB -> 4 blocks/CU by LDS. launch_bounds(512,4): min-waves floor = 4
// (cap 128 regs) -- kernel's natural footprint is ~64 (r11 evidence), so no
// spill, and at <=64 VGPR the HW reaches 8 waves/SIMD anyway. r12's (1024,8)
// and r13's (512,6) capped BELOW the footprint -> 400-800MB spill storms.
__global__ __launch_bounds__(512, 4) void attn_fused(
    const unsigned short* __restrict__ Qb, const unsigned short* __restrict__ K2b,
    const unsigned short* __restrict__ Vtb, const float* __restrict__ inp,
    unsigned short* __restrict__ Hbf) {
  __shared__ __align__(16) char smem[38912];   // 4 x (lk[64][40] | lv[32][72]) shorts
  __shared__ float lbuf[4][64];
  const int tid = threadIdx.x;
  const int lane = tid & 63;
  const int wid = tid >> 6;
  const int qw = wid & 1;
  const int zg = wid >> 1;        // 0..3
  const int kl = lane & 31;
  const int hi = lane >> 5;
  const int gtid = tid & 127;
  const int h = blockIdx.y, hc = h * HDIM;
  const int q_local = qw * 32 + kl;
  const int q = blockIdx.x * 64 + q_local;
  const int ks0 = zg * 1024;

  short* lk = (short*)smem + zg * 4864;            // [64][40]
  short* lv = (short*)smem + zg * 4864 + 2560;     // [32][72]

  const int kkey = gtid >> 1, kslot = gtid & 1;    // K: 2 thr/key, slots {0,1}+{2,3}
  const int vdim = gtid >> 3, vslot = gtid & 7;    // V: dims vdim, vdim+16
  const unsigned short* kg = &K2b[(ks0 + kkey) * DIM + hc + kslot * 16];
  const unsigned short* vg = &Vtb[(hc + vdim) * NN + ks0 + vslot * 8];
  short* lkw = lk + kkey * 40 + kslot * 16;
  short* lvw = lv + vdim * 72 + vslot * 8;

#define LOADKV(KR, VR)                                                      \
  do {                                                                      \
    KR[0] = *(const short8*)(kg);                                           \
    KR[1] = *(const short8*)(kg + 8);                                       \
    VR[0] = *(const short8*)(vg);                                           \
    VR[1] = *(const short8*)(vg + 16 * NN);                                 \
    kg += 64 * DIM; vg += 64;                                               \
  } while (0)
#define STOREKV(KR, VR)                                                     \
  do {                                                                      \
    *(short8*)(lkw) = KR[0];                                                \
    *(short8*)(lkw + 8) = KR[1];                                            \
    *(short8*)(lvw) = VR[0];                                                \
    *(short8*)(lvw + 16 * 72) = VR[1];                                      \
  } while (0)

  short8 qf0 = *(const short8*)&Qb[q * DIM + hc + hi * 8];
  short8 qf1 = *(const short8*)&Qb[q * DIM + hc + 16 + hi * 8];

  f32x16 zc;
#pragma unroll
  for (int r = 0; r < 16; ++r) zc[r] = 0.f;
  f32x16 o = zc;
  float lsum = 0.f;

  short8 kr[2], vr[2];
  LOADKV(kr, vr);
#pragma unroll 1
  for (int t = 0; t < 16; ++t) {
    __syncthreads();                 // all waves done computing previous tile
    STOREKV(kr, vr);                 // (waits on this tile's loads)
    __syncthreads();                 // tile t visible
    if (t < 15) LOADKV(kr, vr);      // issue next tile's loads; land during compute
    compute_tile64(lk, lv, kl, hi, qf0, qf1, zc, o, lsum);
  }
#undef LOADKV
#undef STOREKV

  // in-block merge: o-frags + lsum partials through LDS (aliased over dead K/V tiles)
  float lt = lsum + __shfl_xor(lsum, 32);
  __syncthreads();
  float* mz = (float*)smem + zg * 2208;            // [32 dims][69 q] per group
#pragma unroll
  for (int r = 0; r < 16; ++r) {
    int d = (r & 3) + 8 * (r >> 2) + 4 * hi;
    mz[d * 69 + q_local] = o[r];
  }
  if (hi == 0) lbuf[zg][q_local] = lt;
  __syncthreads();
  {
    int ql = tid >> 3;               // 0..63
    int dg = (tid & 7) * 4;          // 0..28
    float s = (lbuf[0][ql] + lbuf[1][ql]) + (lbuf[2][ql] + lbuf[3][ql]);
    float inv = 1.f / s;
    const float* mb = (const float*)smem;
    float acc[4];
#pragma unroll
    for (int i = 0; i < 4; ++i) {
      int off = (dg + i) * 69 + ql;
      acc[i] = (mb[off] + mb[2208 + off]) + (mb[4416 + off] + mb[6624 + off]);
    }
    int qg = blockIdx.x * 64 + ql;
    float4 in4 = *(const float4*)&inp[qg * DIM + hc + dg];
    ushort4 hb;
    hb.x = bfbits(in4.x + acc[0] * inv);
    hb.y = bfbits(in4.y + acc[1] * inv);
    hb.z = bfbits(in4.z + acc[2] * inv);
    hb.w = bfbits(in4.w + acc[3] * inv);
    *(ushort4*)&Hbf[qg * DIM + hc + dg] = hb;
  }
}

// ---------------- final GEMM (bf16 MFMA): out = H + leaky(H @ Wc + bc) ----------------
// Residual H read back from the staged sA tile (bf16) -- no Hf buffer.
__global__ __launch_bounds__(256) void gemm_final_mfma(
    const unsigned short* __restrict__ Hbf, const unsigned short* __restrict__ Wct,
    const float* __restrict__ bc, float* __restrict__ out) {
  __shared__ __align__(16) short sA[64 * 256];
  __shared__ __align__(16) short sB[64 * 256];
  const int tid = threadIdx.x;
  const int m0 = blockIdx.x * 64;
  const int n0 = blockIdx.y * 64;
#pragma unroll
  for (int i = 0; i < 8; ++i) {
    int idx = i * 256 + tid;
    int row = idx >> 5, slot = idx & 31;
    short8 v = *(const short8*)&Hbf[(m0 + row) * DIM + slot * 8];
    int byte = (slot * 16) ^ ((row & 15) << 4);
    *(short8*)((char*)sA + row * 512 + byte) = v;
  }
#pragma unroll
  for (int i = 0; i < 8; ++i) {
    int idx = i * 256 + tid;
    int row = idx >> 5, slot = idx & 31;
    short8 v = *(const short8*)&Wct[(n0 + row) * DIM + slot * 8];
    int byte = (slot * 16) ^ ((row & 15) << 4);
    *(short8*)((char*)sB + row * 512 + byte) = v;
  }
  __syncthreads();
  const int kl = tid & 31, hi = (tid & 63) >> 5, w = tid >> 6;
  const int rw = (w >> 1) * 32, cw = (w & 1) * 32;
  const int arow = rw + kl, brow = cw + kl;
  const int axor = (arow & 15) << 4, bxor = (brow & 15) << 4;
  const char* apA = (const char*)sA + arow * 512;
  const char* apB = (const char*)sB + brow * 512;
  f32x16 acc;
#pragma unroll
  for (int r = 0; r < 16; ++r) acc[r] = 0.f;
#pragma unroll
  for (int ks = 0; ks < 16; ++ks) {
    int cb = ks * 32 + hi * 16;
    short8 a = *(const short8*)(apA + (cb ^ axor));
    short8 b = *(const short8*)(apB + (cb ^ bxor));
    acc = __builtin_amdgcn_mfma_f32_32x32x16_bf16(a, b, acc, 0, 0, 0);
  }
#pragma unroll
  for (int r = 0; r < 16; ++r) {
    int mrow = (r & 3) + 8 * (r >> 2) + 4 * hi;
    int lrow = rw + mrow;
    int node = m0 + lrow, col = n0 + cw + kl;
    float x = acc[r] + bc[col];
    x = x > 0.f ? x : LEAKY * x;
    // residual from staged sA (Hbf tile, swizzle-consistent ushort read)
    unsigned short hr = *(const unsigned short*)(
        (const char*)sA + lrow * 512 + ((col * 2) ^ ((lrow & 15) << 4)));
    out[node * DIM + col] = bf2f(hr) + x;
  }
}

extern "C" void kernel_launch(void* const* d_in, const int* in_sizes, int n_in,
                              void* d_out, int out_size, void* d_ws, size_t ws_size,
                              hipStream_t stream) {
  const float* inp = (const float*)d_in[0];
  const int* src   = (const int*)d_in[1];
  const int* dst   = (const int*)d_in[2];
  const float* WQ  = (const float*)d_in[3];
  const float* WK  = (const float*)d_in[4];
  const float* WV  = (const float*)d_in[5];
  const float* Wc  = (const float*)d_in[6];
  const float* bc  = (const float*)d_in[7];
  float* out = (float*)d_out;
  const int E = in_sizes[1];

  // ws layout (~12.6 MB):
  char* ws = (char*)d_ws;
  unsigned short* Qb  = (unsigned short*)(ws);                      // 2 MB
  unsigned short* Kb  = (unsigned short*)(ws + 2  * 1024 * 1024);   // 2 MB
  unsigned short* Vtb = (unsigned short*)(ws + 4  * 1024 * 1024);   // 2 MB
  unsigned short* K2b = (unsigned short*)(ws + 6  * 1024 * 1024);   // 2 MB
  unsigned short* Wtb = (unsigned short*)(ws + 8  * 1024 * 1024);   // 512 KB
  unsigned short* Hbf = (unsigned short*)(ws + 8 * 1024 * 1024 + 524288);   // 2 MB
  int* cnt            = (int*)(ws + 10 * 1024 * 1024 + 524288);     // 16 KB
  int* esrc           = (int*)(ws + 10 * 1024 * 1024 + 540672);     // 2 MB (4096 x 128)

  const int fillBlocks = (E + 255) / 256;
  convert_w<<<dim3(16, 4), 256, 0, stream>>>(WQ, WK, WV, Wc, Wtb, cnt);
  gemm_fill<<<256 + fillBlocks, 256, 0, stream>>>(inp, Wtb, src, dst, E, cnt, esrc,
                                                  Qb, Kb, Vtb);
  gather_k2<<<NN / 4, 256, 0, stream>>>(Kb, cnt, esrc, K2b);
  attn_fused<<<dim3(64, 8), 512, 0, stream>>>(Qb, K2b, Vtb, inp, Hbf);
  gemm_final_mfma<<<dim3(64, 4), 256, 0, stream>>>(Hbf, Wtb + 3 * 65536, bc, out);
}